// Round 11
// baseline (3721.261 us; speedup 1.0000x reference)
//
#include <hip/hip_runtime.h>
#include <hip/hip_bf16.h>

#define NN 20000
#define NP 20032            // padded to 32*626
#define NE 320000
#define RR 8
#define DD 256
#define LL 6
#define EED 32
#define BB 64
#define KK 32
#define MM (NN * RR)        // 160000 segments, rel-major key = r*NN + dst
#define NSB 79              // scan blocks: ceil(160000 / 2048)
#define NB2 626             // row blocks of 32
#define HSTR 260            // fp32 LDS tile row stride (floats) — breaks bank aliasing
#define ACCN (32 * HSTR)    // 8320 floats per tile

typedef __bf16 bf8 __attribute__((ext_vector_type(8)));
typedef float f4 __attribute__((ext_vector_type(4)));
union BF8U { bf8 v; unsigned u[4]; };

__device__ inline float lo2f(unsigned v) { return __uint_as_float(v << 16); }
__device__ inline float hi2f(unsigned v) { return __uint_as_float(v & 0xffff0000u); }
__device__ inline unsigned short f2bf(float f) {
    unsigned u = __float_as_uint(f);
    return (unsigned short)((u + 0x7fff + ((u >> 16) & 1)) >> 16);
}
__device__ inline unsigned pack2(float lo, float hi) {
    return (unsigned)f2bf(lo) | ((unsigned)f2bf(hi) << 16);
}

// ---------------- CSR build (once per call), REL-MAJOR ----------------

__global__ __launch_bounds__(256) void hist_kernel(const int* __restrict__ dstv,
                                                   const int* __restrict__ typev,
                                                   int* __restrict__ hist) {
    int e = blockIdx.x * 256 + threadIdx.x;
    if (e < NE) atomicAdd(&hist[typev[e] * NN + dstv[e]], 1);
}

__global__ __launch_bounds__(256) void scan1_kernel(const int* __restrict__ hist,
                                                    int* __restrict__ excl,
                                                    int* __restrict__ bsums) {
    __shared__ int tmp[256];
    int tid = threadIdx.x;
    int base = blockIdx.x * 2048 + tid * 8;
    int v[8]; int s = 0;
#pragma unroll
    for (int i = 0; i < 8; ++i) {
        v[i] = (base + i < MM) ? hist[base + i] : 0;
        s += v[i];
    }
    tmp[tid] = s;
    __syncthreads();
    for (int off = 1; off < 256; off <<= 1) {
        int t = (tid >= off) ? tmp[tid - off] : 0;
        __syncthreads();
        tmp[tid] += t;
        __syncthreads();
    }
    int run = tmp[tid] - s;
#pragma unroll
    for (int i = 0; i < 8; ++i) {
        if (base + i < MM) excl[base + i] = run;
        run += v[i];
    }
    if (tid == 255) bsums[blockIdx.x] = tmp[255];
}

__global__ __launch_bounds__(128) void scan2_kernel(int* __restrict__ bsums) {
    __shared__ int tmp[128];
    int tid = threadIdx.x;
    int orig = (tid < NSB) ? bsums[tid] : 0;
    tmp[tid] = orig;
    __syncthreads();
    for (int off = 1; off < 128; off <<= 1) {
        int t = (tid >= off) ? tmp[tid - off] : 0;
        __syncthreads();
        tmp[tid] += t;
        __syncthreads();
    }
    if (tid < NSB) bsums[tid] = tmp[tid] - orig;
}

__global__ __launch_bounds__(256) void add_off_kernel(const int* __restrict__ excl,
                                                      const int* __restrict__ bsums,
                                                      int* __restrict__ seg_start,
                                                      int* __restrict__ cursor) {
    int i = blockIdx.x * 256 + threadIdx.x;
    if (i < MM) {
        int v = excl[i] + bsums[i >> 11];
        seg_start[i] = v;
        cursor[i] = v;
    }
    if (i == 0) seg_start[MM] = NE;
}

// epack = src | (dst&31)<<16  (src < 2^15, block rows are 32-aligned)
__global__ __launch_bounds__(256) void sort_scatter_kernel(
    const int* __restrict__ srcv, const int* __restrict__ dstv,
    const int* __restrict__ typev, int* __restrict__ cursor,
    int* __restrict__ epack, int* __restrict__ eid) {
    int e = blockIdx.x * 256 + threadIdx.x;
    if (e < NE) {
        int key = typev[e] * NN + dstv[e];
        int pos = atomicAdd(&cursor[key], 1);
        epack[pos] = srcv[e] | ((dstv[e] & 31) << 16);
        eid[pos]  = e;
    }
}

__global__ __launch_bounds__(256) void invdeg_kernel(const int* __restrict__ seg_start,
                                                     float* __restrict__ invdeg) {
    int i = blockIdx.x * 256 + threadIdx.x;
    if (i < NN) {
        int d = 0;
#pragma unroll
        for (int r = 0; r < RR; ++r)
            d += seg_start[r * NN + i + 1] - seg_start[r * NN + i];
        invdeg[i] = 1.0f / (float)max(d, 1);
    }
}

// ---------------- once-per-call precomputes ----------------

__global__ __launch_bounds__(256) void eagg_kernel(
    const int* __restrict__ seg_start, const int* __restrict__ eid,
    const float* __restrict__ ee, const float* __restrict__ invdeg,
    unsigned short* __restrict__ eaggbf) {
    int tid = threadIdx.x;
    int s = blockIdx.x * 8 + (tid >> 5);
    int j = tid & 31;
    int n = s >> 3, r = s & 7;
    int j0 = seg_start[r * NN + n], j1 = seg_start[r * NN + n + 1];
    float sum = 0.0f;
    for (int p = j0; p < j1; ++p)
        sum += ee[eid[p] * EED + j];
    eaggbf[(size_t)n * DD + r * EED + j] = f2bf(sum * invdeg[n]);
}

// Whe split-K over 8 d-chunks of 32, fp32 atomics (Whe pre-zeroed)
__global__ __launch_bounds__(256) void whe_kernel(const float* __restrict__ We,
                                                  const float* __restrict__ W,
                                                  float* __restrict__ Whe) {
    __shared__ float WeS[EED * 32];
    int b = blockIdx.x;
    int l = b >> 6;
    int r = (b >> 3) & 7;
    int dc = b & 7;
    int tid = threadIdx.x;
    {
        int j = tid >> 3, dl = (tid & 7) * 4;
        *(float4*)&WeS[j * 32 + dl] =
            *(const float4*)&We[(size_t)l * EED * DD + (size_t)j * DD + dc * 32 + dl];
    }
    __syncthreads();
    const float* Wr = W + ((size_t)l * 8 + r) * DD * DD + (size_t)dc * 32 * DD;
    float acc[EED];
#pragma unroll
    for (int j = 0; j < EED; ++j) acc[j] = 0.0f;
    for (int dl = 0; dl < 32; ++dl) {
        float w = Wr[(size_t)dl * DD + tid];
#pragma unroll
        for (int j = 0; j < EED; ++j) acc[j] += WeS[j * 32 + dl] * w;
    }
    float* outp = Whe + (size_t)l * DD * DD + r * EED * DD + tid;
#pragma unroll
    for (int j = 0; j < EED; ++j) unsafeAtomicAdd(&outp[j * DD], acc[j]);
}

// B pre-swizzle into MFMA fragment order (bf16).
// Phase order: p=0 -> Wself, p=1..8 -> W[r=p-1], p=9 -> Whe.
__global__ __launch_bounds__(256) void bswz_kernel(const float* __restrict__ W,
                                                   const float* __restrict__ Wself,
                                                   const float* __restrict__ Whe,
                                                   unsigned short* __restrict__ Bsw) {
    int gid = blockIdx.x * 256 + threadIdx.x;
    int f = gid & 255;
    int t = gid >> 8;
    int quad = t & 3; t >>= 2;
    int kb = t & 7; t >>= 3;
    int p = t % 10, l = t / 10;
    const float* base = (p == 0) ? Wself + (size_t)l * DD * DD
                      : (p <= 8) ? W + ((size_t)l * 8 + (p - 1)) * DD * DD
                                 : Whe + (size_t)l * DD * DD;
    int k0 = kb * 32 + quad * 8;
    unsigned pk[4];
#pragma unroll
    for (int jj = 0; jj < 4; ++jj)
        pk[jj] = pack2(base[(size_t)(k0 + 2 * jj) * DD + f],
                       base[(size_t)(k0 + 2 * jj + 1) * DD + f]);
    uint4 v = make_uint4(pk[0], pk[1], pk[2], pk[3]);
    *(uint4*)&Bsw[(size_t)gid * 8] = v;
}

__global__ __launch_bounds__(256) void init_x_kernel(float* __restrict__ x,
                                                     unsigned short* __restrict__ xbf) {
    int i = blockIdx.x * 256 + threadIdx.x;
    ((float4*)x)[i] = make_float4(1.f, 1.f, 1.f, 1.f);
    ((uint2*)xbf)[i] = make_uint2(0x3f803f80u, 0x3f803f80u);
}

// ------- fused per-layer kernel: edge-parallel LDS-atomic gather + MFMA + LN -------
// Block = 32 dst rows x 256 cols, 8 waves (512 thr):
//   waves 0..3 CONSUMERS: MFMA on fp32 tile acc[p&1] (read frag, scale by idg,
//     cvt->bf16 in-register), cols cwave*64; B reg-prefetched 2 g-steps ahead.
//   waves 4..7 PRODUCERS: edge-parallel gather of relation p (rel-major CSR ->
//     contiguous range, equal chunks, batch-4, whole-wave per edge, row from
//     epack) accumulating into fp32 tile acc[(p+1)&1] via LDS ds_add_f32.
// Two barriers/phase: [work] bar1 [all-thread zero of consumed tile] bar2.
__global__ __launch_bounds__(512, 2) void fused_layer_kernel(
    const int* __restrict__ seg_start, const int* __restrict__ epack,
    const unsigned short* __restrict__ xbf, const unsigned short* __restrict__ eaggbf,
    const unsigned short* __restrict__ Bswl, const float* __restrict__ xin,
    const float* __restrict__ invdeg, const float* __restrict__ gl,
    const float* __restrict__ bl, float* __restrict__ xout,
    unsigned short* __restrict__ xbfout) {
    __shared__ __align__(16) float accS[2 * ACCN];   // two 32x260 fp32 tiles
    __shared__ float idgS[32];
    __shared__ int relS[8], relE[8];
    float* Hs = accS;                                // epilogue overlay (32 x HSTR)
    int tid = threadIdx.x;
    int wave = tid >> 6, lane = tid & 63;
    bool consumer = wave < 4;
    int cwave = wave & 3;
    int row0 = blockIdx.x * 32;
    int m = lane & 15, quad = lane >> 4;
    f4 acc[2][4] = {};

    // ---- prologue: bounds, idg, x tile (fp32), zero acc1, B prefetch ----
    if (tid < 8) {
        relS[tid] = seg_start[tid * NN + row0];
        relE[tid] = seg_start[tid * NN + min(row0 + 32, NN)];
    }
    if (tid >= 32 && tid < 64) {
        int rr = tid - 32;
        idgS[rr] = (row0 + rr < NN) ? invdeg[row0 + rr] : 1.0f;
    }
    {
        int row = tid >> 4, cb = (tid & 15) * 16;
        const unsigned short* xr = &xbf[(size_t)(row0 + row) * DD + cb];
        uint4 v0 = *(const uint4*)&xr[0];
        uint4 v1 = *(const uint4*)&xr[8];
        float* d0 = &accS[row * HSTR + cb];
        d0[0] = lo2f(v0.x); d0[1] = hi2f(v0.x); d0[2] = lo2f(v0.y); d0[3] = hi2f(v0.y);
        d0[4] = lo2f(v0.z); d0[5] = hi2f(v0.z); d0[6] = lo2f(v0.w); d0[7] = hi2f(v0.w);
        d0[8] = lo2f(v1.x); d0[9] = hi2f(v1.x); d0[10] = lo2f(v1.y); d0[11] = hi2f(v1.y);
        d0[12] = lo2f(v1.z); d0[13] = hi2f(v1.z); d0[14] = lo2f(v1.w); d0[15] = hi2f(v1.w);
        float4 z = make_float4(0.f, 0.f, 0.f, 0.f);
        float* d1 = &accS[ACCN + row * HSTR + cb];
        *(float4*)&d1[0] = z; *(float4*)&d1[4] = z;
        *(float4*)&d1[8] = z; *(float4*)&d1[12] = z;
    }
    bf8 breg[2][4];
    if (consumer) {
#pragma unroll
        for (int nt = 0; nt < 4; ++nt) {
            breg[0][nt] = *(const bf8*)&Bswl[((size_t)quad * 256 + cwave * 64 + nt * 16 + m) * 8];
            breg[1][nt] = *(const bf8*)&Bswl[((size_t)(4 + quad) * 256 + cwave * 64 + nt * 16 + m) * 8];
        }
    }
    __syncthreads();

    for (int p = 0; p < 10; ++p) {
        float* bufc = accS + (p & 1) * ACCN;
        float* bufn = accS + ((p + 1) & 1) * ACCN;
        if (consumer) {
            bool doScale = (p >= 1 && p <= 8);
#pragma unroll
            for (int kb = 0; kb < 8; ++kb) {
                bf8 afr[2];
#pragma unroll
                for (int mt = 0; mt < 2; ++mt) {
                    int rowl = mt * 16 + m;
                    const float* ap = &bufc[rowl * HSTR + kb * 32 + quad * 8];
                    f4 lo = *(const f4*)ap;
                    f4 hi = *(const f4*)(ap + 4);
                    float sc = doScale ? idgS[rowl] : 1.0f;
                    BF8U u;
                    u.u[0] = pack2(lo[0] * sc, lo[1] * sc);
                    u.u[1] = pack2(lo[2] * sc, lo[3] * sc);
                    u.u[2] = pack2(hi[0] * sc, hi[1] * sc);
                    u.u[3] = pack2(hi[2] * sc, hi[3] * sc);
                    afr[mt] = u.v;
                }
#pragma unroll
                for (int mt = 0; mt < 2; ++mt)
#pragma unroll
                    for (int nt = 0; nt < 4; ++nt)
                        acc[mt][nt] = __builtin_amdgcn_mfma_f32_16x16x32_bf16(
                            afr[mt], breg[kb & 1][nt], acc[mt][nt], 0, 0, 0);
                int gn = p * 8 + kb + 2;
                if (gn < 80) {
#pragma unroll
                    for (int nt = 0; nt < 4; ++nt)
                        breg[kb & 1][nt] = *(const bf8*)&Bswl[((size_t)gn * 4 + quad) * 2048
                                                              + ((size_t)(cwave * 64 + nt * 16 + m)) * 8];
                }
            }
        } else if (p < 8) {
            // producers: relation r=p, contiguous chunk per wave, batch 4
            int j0 = relS[p];
            int cnt = relE[p] - j0;
            int pw = cwave;
            int chunk = (cnt + 3) >> 2;
            int tb = pw * chunk;
            int te = min(tb + chunk, cnt);
            int cofs = lane * 4;
            for (int t = tb; t < te; t += 4) {
                int w[4];
#pragma unroll
                for (int q = 0; q < 4; ++q)
                    w[q] = (t + q < te) ? epack[j0 + t + q] : -1;
                uint2 gvv[4];
#pragma unroll
                for (int q = 0; q < 4; ++q)
                    if (w[q] >= 0)
                        gvv[q] = *(const uint2*)&xbf[(size_t)(w[q] & 0xffff) * DD + cofs];
#pragma unroll
                for (int q = 0; q < 4; ++q)
                    if (w[q] >= 0) {
                        float* rp = &bufn[(w[q] >> 16) * HSTR + cofs];
                        atomicAdd(rp + 0, lo2f(gvv[q].x));
                        atomicAdd(rp + 1, hi2f(gvv[q].x));
                        atomicAdd(rp + 2, lo2f(gvv[q].y));
                        atomicAdd(rp + 3, hi2f(gvv[q].y));
                    }
            }
        } else if (p == 8) {
            // producers: stage eagg rows (fp32 overwrite of zeroed tile)
            int ptid = (wave - 4) * 64 + lane;      // 0..255
            int row = ptid >> 3, cb = (ptid & 7) * 32;
            const unsigned short* er = &eaggbf[(size_t)(row0 + row) * DD + cb];
            float* d = &bufn[row * HSTR + cb];
#pragma unroll
            for (int c = 0; c < 4; ++c) {
                uint4 v = *(const uint4*)&er[c * 8];
                d[c * 8 + 0] = lo2f(v.x); d[c * 8 + 1] = hi2f(v.x);
                d[c * 8 + 2] = lo2f(v.y); d[c * 8 + 3] = hi2f(v.y);
                d[c * 8 + 4] = lo2f(v.z); d[c * 8 + 5] = hi2f(v.z);
                d[c * 8 + 6] = lo2f(v.w); d[c * 8 + 7] = hi2f(v.w);
            }
        }
        __syncthreads();   // bar1: consumer reads + producer adds done
        if (p < 9) {       // zero consumed tile with ALL 512 threads
            int row = tid >> 4, cb = (tid & 15) * 16;
            float4 z = make_float4(0.f, 0.f, 0.f, 0.f);
            float* d = &bufc[row * HSTR + cb];
            *(float4*)&d[0] = z; *(float4*)&d[4] = z;
            *(float4*)&d[8] = z; *(float4*)&d[12] = z;
        }
        __syncthreads();   // bar2: zeroed tile visible for next phase's producers
    }

    // ---- epilogue: residual prefetch; h tile through LDS; LN+ReLU+residual ----
    float4 xvr[4];
#pragma unroll
    for (int rr = 0; rr < 4; ++rr) {
        int row = wave * 4 + rr;
        xvr[rr] = *(const float4*)&xin[(size_t)(row0 + row) * DD + lane * 4];
    }
    float4 g  = *(const float4*)&gl[lane * 4];
    float4 bb = *(const float4*)&bl[lane * 4];
    if (consumer) {
#pragma unroll
        for (int mt = 0; mt < 2; ++mt)
#pragma unroll
            for (int nt = 0; nt < 4; ++nt)
#pragma unroll
                for (int rg = 0; rg < 4; ++rg)
                    Hs[(mt * 16 + quad * 4 + rg) * HSTR + cwave * 64 + nt * 16 + m] = acc[mt][nt][rg];
    }
    __syncthreads();
#pragma unroll
    for (int rr = 0; rr < 4; ++rr) {
        int row = wave * 4 + rr;
        float4 v = *(float4*)&Hs[row * HSTR + lane * 4];
        float s = v.x + v.y + v.z + v.w;
        float q = v.x * v.x + v.y * v.y + v.z * v.z + v.w * v.w;
#pragma unroll
        for (int off = 32; off; off >>= 1) {
            s += __shfl_xor(s, off);
            q += __shfl_xor(q, off);
        }
        float mu  = s * (1.0f / DD);
        float var = q * (1.0f / DD) - mu * mu;
        float rs  = rsqrtf(var + 1e-5f);
        size_t xi = (size_t)(row0 + row) * DD + lane * 4;
        float4 xv = xvr[rr];
        float4 o;
        o.x = fmaxf((v.x - mu) * rs * g.x + bb.x, 0.0f) + xv.x;
        o.y = fmaxf((v.y - mu) * rs * g.y + bb.y, 0.0f) + xv.y;
        o.z = fmaxf((v.z - mu) * rs * g.z + bb.z, 0.0f) + xv.z;
        o.w = fmaxf((v.w - mu) * rs * g.w + bb.w, 0.0f) + xv.w;
        *(float4*)&xout[xi] = o;
        *(uint2*)&xbfout[xi] = make_uint2(pack2(o.x, o.y), pack2(o.z, o.w));
    }
}

__global__ __launch_bounds__(256) void score_kernel(
    const int* __restrict__ batch, const float* __restrict__ x,
    const float* __restrict__ rel_emb, float* __restrict__ out) {
    int tid = threadIdx.x;
    int wave = tid >> 6, lane = tid & 63;
    int idx = blockIdx.x * 4 + wave;
    int s = batch[idx * 3 + 0], t = batch[idx * 3 + 1], r = batch[idx * 3 + 2];
    float4 sv = *(const float4*)&x[(size_t)s * DD + lane * 4];
    float4 tv = *(const float4*)&x[(size_t)t * DD + lane * 4];
    float4 rv = *(const float4*)&rel_emb[(size_t)r * DD + lane * 4];
    float sum = sv.x * rv.x * tv.x + sv.y * rv.y * tv.y +
                sv.z * rv.z * tv.z + sv.w * rv.w * tv.w;
#pragma unroll
    for (int off = 32; off; off >>= 1) sum += __shfl_xor(sum, off);
    if (lane == 0) out[idx] = sum;
}

extern "C" void kernel_launch(void* const* d_in, const int* in_sizes, int n_in,
                              void* d_out, int out_size, void* d_ws, size_t ws_size,
                              hipStream_t stream) {
    const int*   edge_index = (const int*)d_in[0];
    const int*   srcv   = edge_index;
    const int*   dstv   = edge_index + NE;
    const int*   typev  = (const int*)d_in[1];
    const float* ee     = (const float*)d_in[2];
    const int*   batch  = (const int*)d_in[3];
    const float* W      = (const float*)d_in[4];
    const float* Wself  = (const float*)d_in[5];
    const float* We     = (const float*)d_in[6];
    const float* gamma  = (const float*)d_in[7];
    const float* beta   = (const float*)d_in[8];
    const float* rel_emb= (const float*)d_in[9];
    float* out = (float*)d_out;

    // workspace layout
    float* xA     = (float*)d_ws;                          // NP*256 f32
    float* xB     = xA + (size_t)NP * DD;                  // NP*256 f32
    float* Whe    = xB + (size_t)NP * DD;                  // L*256*256 f32
    float* invdeg = Whe + (size_t)LL * DD * DD;            // NN f32
    unsigned short* xbfA   = (unsigned short*)(invdeg + NN);          // NP*256
    unsigned short* xbfB   = xbfA + (size_t)NP * DD;                  // NP*256
    unsigned short* eaggbf = xbfB + (size_t)NP * DD;                  // NP*256
    unsigned short* Bsw    = eaggbf + (size_t)NP * DD;                // L*2560*256
    int* hist      = (int*)(Bsw + (size_t)LL * 2560 * DD);            // M
    int* excl      = hist + MM;
    int* seg_start = excl + MM;                                       // M+1
    int* cursor    = seg_start + MM + 1;
    int* bsums     = cursor + MM;                                     // 256
    int* epack     = bsums + 256;                                     // E
    int* eid       = epack + NE;                                      // E

    // ---- CSR build (rel-major) ----
    hipMemsetAsync(hist, 0, MM * sizeof(int), stream);
    hist_kernel<<<(NE + 255) / 256, 256, 0, stream>>>(dstv, typev, hist);
    scan1_kernel<<<NSB, 256, 0, stream>>>(hist, excl, bsums);
    scan2_kernel<<<1, 128, 0, stream>>>(bsums);
    add_off_kernel<<<(MM + 255) / 256, 256, 0, stream>>>(excl, bsums, seg_start, cursor);
    invdeg_kernel<<<(NN + 255) / 256, 256, 0, stream>>>(seg_start, invdeg);
    sort_scatter_kernel<<<(NE + 255) / 256, 256, 0, stream>>>(srcv, dstv, typev, cursor, epack, eid);

    // ---- precomputes ----
    eagg_kernel<<<MM / 8, 256, 0, stream>>>(seg_start, eid, ee, invdeg, eaggbf);
    hipMemsetAsync(Whe, 0, (size_t)LL * DD * DD * sizeof(float), stream);
    whe_kernel<<<LL * 64, 256, 0, stream>>>(We, W, Whe);
    bswz_kernel<<<LL * 10 * 8 * 4, 256, 0, stream>>>(W, Wself, Whe, Bsw);
    init_x_kernel<<<(NP * DD / 4) / 256, 256, 0, stream>>>(xA, xbfA);

    // ---- layers (x double-buffered), edge-parallel fused kernel ----
    float* xin = xA;  float* xout = xB;
    unsigned short* xbin = xbfA;  unsigned short* xbout = xbfB;
    for (int l = 0; l < LL; ++l) {
        fused_layer_kernel<<<NB2, 512, 0, stream>>>(seg_start, epack, xbin, eaggbf,
            Bsw + (size_t)l * 2560 * DD, xin, invdeg,
            gamma + (size_t)l * DD, beta + (size_t)l * DD, xout, xbout);
        float* t = xin; xin = xout; xout = t;
        unsigned short* tb = xbin; xbin = xbout; xbout = tb;
    }
    score_kernel<<<(BB * KK) / 4, 256, 0, stream>>>(batch, xin, rel_emb, out);
}